// Round 4
// baseline (2708.307 us; speedup 1.0000x reference)
//
#include <hip/hip_runtime.h>
#include <stdint.h>

typedef __attribute__((ext_vector_type(4))) int   i32x4;
typedef __attribute__((ext_vector_type(8))) short bf16x8;
typedef __attribute__((ext_vector_type(4))) float f32x4;

#define DEV static __device__ __forceinline__

constexpr int  kB = 128, kT = 512, kD = 512, kH = 512;
constexpr int  kGC = 2048;               // 4*H
constexpr int  ROWS = 32;                // batch rows per block
constexpr int  NG = 4;                   // batch groups
constexpr int  NJ = 32;                  // column-slice blocks per cluster
constexpr int  NTHREADS = 512;
constexpr size_t SLOT_ELEMS = (size_t)kB * kH;            // bf16 elems per ring slot -> 128 KB
constexpr size_t WIMG_ELEMS = (size_t)2 * NJ * 4 * 32 * 512; // 4,194,304 bf16
constexpr size_t WIMG_BYTES = WIMG_ELEMS * 2;             // 8 MB
constexpr int  RFULL = kT + 1;           // 513
constexpr int  FLAG_STRIDE = 128;        // one cacheline per (l,g,t); bytes 0..31 used (one per j)
constexpr size_t FLAG_TOTAL = (size_t)2 * NG * kT * FLAG_STRIDE; // 512 KB

DEV ushort f2bf(float f) {
  uint32_t u = __float_as_uint(f);
  u += 0x7fff + ((u >> 16) & 1);        // round-to-nearest-even
  return (ushort)(u >> 16);
}
DEV int pk2(float a, float b) { return (int)((uint32_t)f2bf(a) | ((uint32_t)f2bf(b) << 16)); }
DEV float sigf(float v)  { return 1.f / (1.f + __expf(-v)); }
DEV float tanhf_(float v){ return 1.f - 2.f / (__expf(2.f * v) + 1.f); }

DEV uint64_t ald64(const uint64_t* p) {
  return __hip_atomic_load(p, __ATOMIC_RELAXED, __HIP_MEMORY_SCOPE_AGENT);
}

// Wave-uniform broadcast poll: ALL lanes load the SAME 32-byte flag region.
DEV void poll32(const uint8_t* fb) {
  const uint64_t* p = reinterpret_cast<const uint64_t*>(fb);
  constexpr uint64_t ONE = 0x0101010101010101ull;
  for (;;) {
    uint64_t a = ald64(p) & ald64(p + 1) & ald64(p + 2) & ald64(p + 3);
    if (a == ONE) return;
    __builtin_amdgcn_s_sleep(1);
  }
}

// ---- prep: W (L,1024,2048) fp32 -> bf16 MFMA B-fragment image ----
__global__ void prep_w(const float* __restrict__ W, ushort* __restrict__ wimg) {
  uint32_t idx = blockIdx.x * 256u + threadIdx.x;
  int e = idx & 7, lane = (idx >> 3) & 63, ks = (idx >> 9) & 31;
  int G = (idx >> 14) & 3, j = (idx >> 16) & 31, l = (idx >> 21) & 1;
  int k = ks * 32 + ((lane >> 4) << 3) + e;
  int c = G * 512 + j * 16 + (lane & 15);
  wimg[idx] = f2bf(W[(size_t)l * 1024 * 2048 + (size_t)k * 2048 + c]);
}

// ---- prep: initial h (hiddens[l][0]) fp32 -> ring slot 0 bf16 ----
__global__ void prep_init(const float* __restrict__ hiddens, ushort* __restrict__ r0, ushort* __restrict__ r1) {
  uint32_t idx = blockIdx.x * 256u + threadIdx.x;   // 0 .. 2*65536-1
  int l = idx >> 16; uint32_t r = idx & 65535u;
  ushort v = f2bf(hiddens[(size_t)(l * 2 + 0) * 65536 + r]);
  (l ? r1 : r0)[r] = v;
}

// Bulk-stage 32 rows x 512 cols bf16 from a ring slot into a swizzled LDS half-tile.
DEV void stage_h(ushort* Ab, const ushort* rbase, int g, int tid) {
  #pragma unroll
  for (int p = 0; p < 4; ++p) {
    int o = (tid + p * NTHREADS) * 16, row = o >> 10, kb = o & 1023;
    i32x4 v = *reinterpret_cast<const i32x4*>(rbase + (size_t)(g * ROWS + row) * kH + (kb >> 1));
    *reinterpret_cast<i32x4*>(reinterpret_cast<char*>(Ab) + ((row * 1024 + kb) ^ ((row & 7) << 4))) = v;
  }
}

// Half-cooperative stage: same as stage_h but only 4 waves (256 threads) do it,
// 8 chunks each. tid256 in [0,256).
DEV void stage_h256(ushort* Ab, const ushort* rbase, int g, int tid256) {
  #pragma unroll
  for (int p = 0; p < 8; ++p) {
    int o = (tid256 + p * 256) * 16, row = o >> 10, kb = o & 1023;
    i32x4 v = *reinterpret_cast<const i32x4*>(rbase + (size_t)(g * ROWS + row) * kH + (kb >> 1));
    *reinterpret_cast<i32x4*>(reinterpret_cast<char*>(Ab) + ((row * 1024 + kb) ^ ((row & 7) << 4))) = v;
  }
}

// ======================= BIG path: K-half wave pipeline =======================
// Wave roles (8 waves): wv = kh*4 + Gp*2 + rf
//   kh = wv>>2      : 0 -> x half (K 0..511), 1 -> recurrent half (K 512..1023)
//   Gp = (wv>>1)&1  : gate pair {2Gp, 2Gp+1}
//   rf = wv&1       : row fragment (16 rows)
// Each wave: 16 ds_read_b128, each feeding TWO mfma (2 gates share the A frag).
__launch_bounds__(NTHREADS, 2)
__global__ void lstm_v4(const float* __restrict__ x, const float* __restrict__ hiddens,
                        const float* __restrict__ bias, const ushort* __restrict__ wimg,
                        ushort* __restrict__ ring0, ushort* __restrict__ ring1,
                        uint8_t* __restrict__ flags, float* __restrict__ out) {
  __shared__ ushort AbufX[ROWS * 512];    // 32 KB: input half (k=0..511)
  __shared__ ushort AbufH[ROWS * 512];    // 32 KB: recurrent half (k=512..1023)
  __shared__ float  gbuf[2][4][ROWS][17]; // raw gate partials [kh][gate][row][col]

  const int tid  = threadIdx.x;
  const int lane = tid & 63;
  const int wv   = tid >> 6;
  const int kh   = wv >> 2;               // K-half
  const int Gp   = (wv >> 1) & 1;         // gate pair
  const int rf   = wv & 1;                // row-fragment (16 rows)
  const int j    = blockIdx.x & 31;       // column slice
  const int g    = (blockIdx.x >> 5) & 3; // batch group
  const int l    = blockIdx.x >> 7;       // layer

  __threadfence();  // entry agent fence: kill cross-replay stale cache lines

  // W fragments: 2 gates x 16 ksteps of this wave's K-half (128 regs)
  i32x4 wrA[16], wrB[16];
  {
    const int GA = 2 * Gp, GB = 2 * Gp + 1;
    const ushort* baseA = wimg + (((size_t)(l * NJ + j) * 4 + GA) * 32 + kh * 16) * 512 + lane * 8;
    const ushort* baseB = wimg + (((size_t)(l * NJ + j) * 4 + GB) * 32 + kh * 16) * 512 + lane * 8;
    #pragma unroll
    for (int ks = 0; ks < 16; ++ks) {
      wrA[ks] = *reinterpret_cast<const i32x4*>(baseA + ks * 512);
      wrB[ks] = *reinterpret_cast<const i32x4*>(baseB + ks * 512);
    }
  }
  // per-update-thread bias (4 gates) and cell state
  const int urow = tid >> 4, ucol = tid & 15;
  const float b0 = bias[l * kGC + 0 * 512 + j * 16 + ucol];
  const float b1 = bias[l * kGC + 1 * 512 + j * 16 + ucol];
  const float b2 = bias[l * kGC + 2 * 512 + j * 16 + ucol];
  const float b3 = bias[l * kGC + 3 * 512 + j * 16 + ucol];
  float creg = hiddens[((size_t)(l * 2 + 1) * kB + (g * ROWS + urow)) * kH + j * 16 + ucol];

  ushort* rrec = l ? ring1 : ring0;
  uint8_t* myflags = flags + (size_t)(l * NG + g) * kT * FLAG_STRIDE;
  const uint8_t* xflags = flags + (size_t)g * kT * FLAG_STRIDE;  // layer-0 cluster

  const int arow  = rf * 16 + (lane & 15);
  const int koff  = (lane >> 4) << 3;
  const int abase = arow * 1024;
  const int aswz  = (arow & 7) << 4;

  // x-prefetch registers (layer 0 only): one step's 32x512 f32 tile, 128B/thread
  f32x4 xr[8];
  if (l == 0) {
    #pragma unroll
    for (int p = 0; p < 4; ++p) {
      int o = (tid + p * NTHREADS) * 16, row = o >> 10, kb = o & 1023;
      const float* src = x + ((size_t)(g * ROWS + row) * kT + 0) * kD + (kb >> 1);
      xr[2 * p]     = *reinterpret_cast<const f32x4*>(src);
      xr[2 * p + 1] = *reinterpret_cast<const f32x4*>(src + 4);
    }
  }

  for (int t = 0; t < kT; ++t) {
    // ---------- top: AbufX ready-up ----------
    if (l == 0) {
      #pragma unroll
      for (int p = 0; p < 4; ++p) {
        int o = (tid + p * NTHREADS) * 16, row = o >> 10, kb = o & 1023;
        i32x4 v;
        v[0] = pk2(xr[2 * p][0], xr[2 * p][1]);  v[1] = pk2(xr[2 * p][2], xr[2 * p][3]);
        v[2] = pk2(xr[2 * p + 1][0], xr[2 * p + 1][1]); v[3] = pk2(xr[2 * p + 1][2], xr[2 * p + 1][3]);
        *reinterpret_cast<i32x4*>(reinterpret_cast<char*>(AbufX) + ((row * 1024 + kb) ^ ((row & 7) << 4))) = v;
      }
    } else {
      poll32(xflags + (size_t)t * FLAG_STRIDE);        // layer0 finished step t
      stage_h(AbufX, ring0 + (size_t)(t + 1) * SLOT_ELEMS, g, tid);
    }
    __syncthreads();                                   // S1: AbufX ready

    // ---------- kh0: x-half MFMA  |  kh1: poll + stage AbufH ----------
    if (kh == 0) {
      f32x4 accA = {}, accB = {};
      #pragma unroll
      for (int ks = 0; ks < 16; ++ks) {
        int off = (abase + ((ks * 32 + koff) << 1)) ^ aswz;
        i32x4 av = *reinterpret_cast<const i32x4*>(reinterpret_cast<const char*>(AbufX) + off);
        accA = __builtin_amdgcn_mfma_f32_16x16x32_bf16(
                 *reinterpret_cast<bf16x8*>(&av), *reinterpret_cast<bf16x8*>(&wrA[ks]), accA, 0, 0, 0);
        accB = __builtin_amdgcn_mfma_f32_16x16x32_bf16(
                 *reinterpret_cast<bf16x8*>(&av), *reinterpret_cast<bf16x8*>(&wrB[ks]), accB, 0, 0, 0);
      }
      #pragma unroll
      for (int q = 0; q < 4; ++q) {
        int r = rf * 16 + ((lane >> 4) << 2) + q, c = lane & 15;
        gbuf[0][2 * Gp][r][c]     = accA[q];
        gbuf[0][2 * Gp + 1][r][c] = accB[q];
      }
    } else {
      if (t > 0) poll32(myflags + (size_t)(t - 1) * FLAG_STRIDE);
      stage_h256(AbufH, rrec + (size_t)t * SLOT_ELEMS, g, tid - 256);
    }
    __syncthreads();                                   // S2: AbufH ready, gbuf[0] written

    // ---------- x-prefetch issue for t+1 (loads overlap kh1 MFMA + update) ----------
    if (l == 0 && t + 1 < kT) {
      #pragma unroll
      for (int p = 0; p < 4; ++p) {
        int o = (tid + p * NTHREADS) * 16, row = o >> 10, kb = o & 1023;
        const float* src = x + ((size_t)(g * ROWS + row) * kT + (t + 1)) * kD + (kb >> 1);
        xr[2 * p]     = *reinterpret_cast<const f32x4*>(src);
        xr[2 * p + 1] = *reinterpret_cast<const f32x4*>(src + 4);
      }
    }

    // ---------- kh1: recurrent-half MFMA ----------
    if (kh == 1) {
      f32x4 accA = {}, accB = {};
      #pragma unroll
      for (int ks = 0; ks < 16; ++ks) {
        int off = (abase + ((ks * 32 + koff) << 1)) ^ aswz;
        i32x4 av = *reinterpret_cast<const i32x4*>(reinterpret_cast<const char*>(AbufH) + off);
        accA = __builtin_amdgcn_mfma_f32_16x16x32_bf16(
                 *reinterpret_cast<bf16x8*>(&av), *reinterpret_cast<bf16x8*>(&wrA[ks]), accA, 0, 0, 0);
        accB = __builtin_amdgcn_mfma_f32_16x16x32_bf16(
                 *reinterpret_cast<bf16x8*>(&av), *reinterpret_cast<bf16x8*>(&wrB[ks]), accB, 0, 0, 0);
      }
      #pragma unroll
      for (int q = 0; q < 4; ++q) {
        int r = rf * 16 + ((lane >> 4) << 2) + q, c = lane & 15;
        gbuf[1][2 * Gp][r][c]     = accA[q];
        gbuf[1][2 * Gp + 1][r][c] = accB[q];
      }
    }
    __syncthreads();                                   // S3: all partials ready

    // ---------- fused sum + activation + c/h update + publish ----------
    float hh;
    {
      float iv = sigf  (gbuf[0][0][urow][ucol] + gbuf[1][0][urow][ucol] + b0);
      float fv = sigf  (gbuf[0][1][urow][ucol] + gbuf[1][1][urow][ucol] + b1);
      float gv = tanhf_(gbuf[0][2][urow][ucol] + gbuf[1][2][urow][ucol] + b2);
      float ov = sigf  (gbuf[0][3][urow][ucol] + gbuf[1][3][urow][ucol] + b3);
      creg = fv * creg + iv * gv;
      hh = ov * tanhf_(creg);
      uint32_t me    = f2bf(hh);
      uint32_t other = (uint32_t)__shfl_xor((int)me, 1);  // partner col^1, same wave
      if (!(ucol & 1)) {
        uint32_t pkv = me | (other << 16);
        uint32_t* dst = (uint32_t*)(rrec + (size_t)(t + 1) * SLOT_ELEMS
                                    + (size_t)(g * ROWS + urow) * kH + j * 16 + ucol);
        __hip_atomic_store(dst, pkv, __ATOMIC_RELAXED, __HIP_MEMORY_SCOPE_AGENT);
      }
    }
    asm volatile("s_waitcnt vmcnt(0)" ::: "memory");   // drain publish stores (xr loads too — done by now)
    __syncthreads();                                   // S_p: all waves drained
    if (tid == 0)
      __hip_atomic_store(myflags + (size_t)t * FLAG_STRIDE + j, (uint8_t)1,
                         __ATOMIC_RELAXED, __HIP_MEMORY_SCOPE_AGENT);

    // bulk output writes AFTER the flag
    {
      int b = g * ROWS + urow;
      if (l == 1) out[((size_t)b * kT + t) * kH + j * 16 + ucol] = hh;
      if (t == kT - 1) {
        size_t hb = (size_t)kB * kT * kH;
        out[hb + ((size_t)(l * 2 + 0) * kB + b) * kH + j * 16 + ucol] = hh;
        out[hb + ((size_t)(l * 2 + 1) * kB + b) * kH + j * 16 + ucol] = creg;
      }
    }
  }
}

// ======================= small-workspace fallback (round-0 proven path) =======================

template<bool BIG>
DEV void stage_ring(ushort* Abuf_, const ushort* rbase, int g, int tid) {
  #pragma unroll
  for (int p = 0; p < 4; ++p) {
    int o = (tid + p * NTHREADS) * 16;
    int row = o >> 10, kb = o & 1023;
    const ushort* src = rbase + (size_t)(g * ROWS + row) * kH + (kb >> 1);
    i32x4 v;
    if (BIG) {
      v = *reinterpret_cast<const i32x4*>(src);
    } else {
      uint64_t lo = __hip_atomic_load((const uint64_t*)src,       __ATOMIC_RELAXED, __HIP_MEMORY_SCOPE_AGENT);
      uint64_t hi = __hip_atomic_load((const uint64_t*)(src + 4), __ATOMIC_RELAXED, __HIP_MEMORY_SCOPE_AGENT);
      v[0] = (int)(uint32_t)lo; v[1] = (int)(uint32_t)(lo >> 32);
      v[2] = (int)(uint32_t)hi; v[3] = (int)(uint32_t)(hi >> 32);
    }
    *reinterpret_cast<i32x4*>(reinterpret_cast<char*>(Abuf_) + ((row * 1024 + kb) ^ ((row & 7) << 4))) = v;
  }
}

template<bool BIG>
__launch_bounds__(NTHREADS, 2)
__global__ void lstm_main(const float* __restrict__ x, const float* __restrict__ hiddens,
                          const float* __restrict__ bias, const ushort* __restrict__ wimg,
                          ushort* __restrict__ ring0, ushort* __restrict__ ring1,
                          int* __restrict__ cnt, int* __restrict__ cons0,
                          float* __restrict__ out, int R0, int R1) {
  __shared__ ushort Abuf[ROWS * 512];
  __shared__ float  gbuf[4][ROWS][16];
  __shared__ float  cbuf[ROWS][16];
  __shared__ float  hbuf[ROWS][16];

  const int tid  = threadIdx.x;
  const int lane = tid & 63;
  const int wv   = tid >> 6;
  const int G    = wv & 3;
  const int rf   = wv >> 2;
  const int j    = blockIdx.x & 31;
  const int g    = (blockIdx.x >> 5) & 3;
  const int l    = blockIdx.x >> 7;

  __threadfence();

  i32x4 wr[32];
  {
    const ushort* base = wimg + (((size_t)(l * NJ + j) * 4 + G) * 32) * 512 + lane * 8;
    #pragma unroll
    for (int ks = 0; ks < 32; ++ks)
      wr[ks] = *reinterpret_cast<const i32x4*>(base + ks * 512);
  }
  const float bval = bias[l * kGC + G * 512 + j * 16 + (lane & 15)];
  {
    int row = tid >> 4, col = tid & 15;
    cbuf[row][col] = hiddens[((size_t)(l * 2 + 1) * kB + (g * ROWS + row)) * kH + j * 16 + col];
  }
  int* mycnt = cnt + (l * NG + g) * kT;
  int* c0cnt = cnt + g * kT;
  ushort* rrec = l ? ring1 : ring0;
  const int Rrec = l ? R1 : R0;

  const int arow  = rf * 16 + (lane & 15);
  const int koff  = (lane >> 4) << 3;
  const int abase = arow * 1024;
  const int aswz  = (arow & 7) << 4;

  __syncthreads();

  for (int t = 0; t < kT; ++t) {
    if (l == 1) {
      if (tid == 0) {
        while (__hip_atomic_load(&c0cnt[t], __ATOMIC_RELAXED, __HIP_MEMORY_SCOPE_AGENT) < NJ)
          __builtin_amdgcn_s_sleep(2);
      }
      __syncthreads();
      stage_ring<BIG>(Abuf, ring0 + (size_t)((t + 1) % R0) * SLOT_ELEMS, g, tid);
    } else {
      #pragma unroll
      for (int p = 0; p < 4; ++p) {
        int o = (tid + p * NTHREADS) * 16;
        int row = o >> 10, kb = o & 1023;
        const float* src = x + ((size_t)(g * ROWS + row) * kT + t) * kD + (kb >> 1);
        f32x4 f0 = *reinterpret_cast<const f32x4*>(src);
        f32x4 f1 = *reinterpret_cast<const f32x4*>(src + 4);
        i32x4 v;
        v[0] = pk2(f0[0], f0[1]); v[1] = pk2(f0[2], f0[3]);
        v[2] = pk2(f1[0], f1[1]); v[3] = pk2(f1[2], f1[3]);
        *reinterpret_cast<i32x4*>(reinterpret_cast<char*>(Abuf) + ((row * 1024 + kb) ^ ((row & 7) << 4))) = v;
      }
    }
    __syncthreads();
    if (!BIG && l == 1 && tid == 0)
      __hip_atomic_fetch_add(&cons0[g * kT + t], 1, __ATOMIC_RELAXED, __HIP_MEMORY_SCOPE_AGENT);

    f32x4 acc = {};
    #pragma unroll
    for (int ks = 0; ks < 16; ++ks) {
      int off = (abase + ((ks * 32 + koff) << 1)) ^ aswz;
      i32x4 av = *reinterpret_cast<const i32x4*>(reinterpret_cast<const char*>(Abuf) + off);
      acc = __builtin_amdgcn_mfma_f32_16x16x32_bf16(
              *reinterpret_cast<bf16x8*>(&av), *reinterpret_cast<bf16x8*>(&wr[ks]), acc, 0, 0, 0);
    }
    __syncthreads();

    if (t > 0) {
      if (tid == 0) {
        while (__hip_atomic_load(&mycnt[t - 1], __ATOMIC_RELAXED, __HIP_MEMORY_SCOPE_AGENT) < NJ)
          __builtin_amdgcn_s_sleep(2);
        if (!BIG && l == 0 && t >= R0) {
          while (__hip_atomic_load(&cons0[g * kT + (t - R0)], __ATOMIC_RELAXED, __HIP_MEMORY_SCOPE_AGENT) < NJ)
            __builtin_amdgcn_s_sleep(2);
        }
      }
      __syncthreads();
    }
    stage_ring<BIG>(Abuf, rrec + (size_t)(t % Rrec) * SLOT_ELEMS, g, tid);
    __syncthreads();

    #pragma unroll
    for (int ks = 0; ks < 16; ++ks) {
      int off = (abase + ((ks * 32 + koff) << 1)) ^ aswz;
      i32x4 av = *reinterpret_cast<const i32x4*>(reinterpret_cast<const char*>(Abuf) + off);
      acc = __builtin_amdgcn_mfma_f32_16x16x32_bf16(
              *reinterpret_cast<bf16x8*>(&av), *reinterpret_cast<bf16x8*>(&wr[16 + ks]), acc, 0, 0, 0);
    }

    #pragma unroll
    for (int q = 0; q < 4; ++q) {
      float v2 = acc[q] + bval;
      v2 = (G == 2) ? tanhf_(v2) : sigf(v2);
      gbuf[G][rf * 16 + ((lane >> 4) << 2) + q][lane & 15] = v2;
    }
    __syncthreads();

    {
      int row = tid >> 4, col = tid & 15;
      float iv = gbuf[0][row][col], fv = gbuf[1][row][col];
      float gv = gbuf[2][row][col], ov = gbuf[3][row][col];
      float cc = fv * cbuf[row][col] + iv * gv;
      cbuf[row][col] = cc;
      float hh = ov * tanhf_(cc);
      hbuf[row][col] = hh;
      int b = g * ROWS + row;
      if (l == 1) out[((size_t)b * kT + t) * kH + j * 16 + col] = hh;
      if (t == kT - 1) {
        size_t hb = (size_t)kB * kT * kH;
        out[hb + ((size_t)(l * 2 + 0) * kB + b) * kH + j * 16 + col] = hh;
        out[hb + ((size_t)(l * 2 + 1) * kB + b) * kH + j * 16 + col] = cc;
      }
    }
    __syncthreads();

    if (tid < 256) {
      int row = tid >> 3, cp = tid & 7;
      uint32_t pkv = (uint32_t)f2bf(hbuf[row][2 * cp]) | ((uint32_t)f2bf(hbuf[row][2 * cp + 1]) << 16);
      uint32_t* dst = (uint32_t*)(rrec + (size_t)((t + 1) % Rrec) * SLOT_ELEMS
                                  + (size_t)(g * ROWS + row) * kH + j * 16 + 2 * cp);
      __hip_atomic_store(dst, pkv, __ATOMIC_RELAXED, __HIP_MEMORY_SCOPE_AGENT);
    }
    asm volatile("s_waitcnt vmcnt(0)" ::: "memory");
    __syncthreads();
    if (tid == 0)
      __hip_atomic_fetch_add(&mycnt[t], 1, __ATOMIC_RELAXED, __HIP_MEMORY_SCOPE_AGENT);
  }
}

extern "C" void kernel_launch(void* const* d_in, const int* in_sizes, int n_in,
                              void* d_out, int out_size, void* d_ws, size_t ws_size,
                              hipStream_t stream) {
  const float* x  = (const float*)d_in[0];
  const float* hd = (const float*)d_in[1];
  const float* W  = (const float*)d_in[2];
  const float* b  = (const float*)d_in[3];
  float* out = (float*)d_out;

  char* ws = (char*)d_ws;
  ushort* wimg = (ushort*)ws;
  uint8_t* flags = (uint8_t*)(ws + WIMG_BYTES);                // 512 KB
  int* cnt  = (int*)(ws + WIMG_BYTES + FLAG_TOTAL);            // 16 KB (fallback)
  int* cons = (int*)(ws + WIMG_BYTES + FLAG_TOTAL + 16384);    // 8 KB  (fallback)
  size_t ringoff = WIMG_BYTES + FLAG_TOTAL + 32768;
  size_t avail = ws_size > ringoff ? ws_size - ringoff : 0;
  long rmax = (long)(avail / (2 * SLOT_ELEMS * 2));
  int R = (rmax >= RFULL) ? RFULL : (rmax >= 16 ? 16 : (rmax >= 2 ? (int)rmax : 2));
  ushort* ring0 = (ushort*)(ws + ringoff);
  ushort* ring1 = ring0 + (size_t)R * SLOT_ELEMS;

  prep_w<<<(int)(WIMG_ELEMS / 256), 256, 0, stream>>>(W, wimg);
  prep_init<<<(2 * kB * kH) / 256, 256, 0, stream>>>(hd, ring0, ring1);
  if (R == RFULL) {
    hipMemsetAsync(flags, 0, FLAG_TOTAL, stream);
    lstm_v4<<<256, NTHREADS, 0, stream>>>(x, hd, b, wimg, ring0, ring1, flags, out);
  } else {
    hipMemsetAsync(ws + WIMG_BYTES + FLAG_TOTAL, 0, 32768, stream);
    lstm_main<false><<<256, NTHREADS, 0, stream>>>(x, hd, b, wimg, ring0, ring1, cnt, cons, out, R, R);
  }
}

// Round 5
// 2055.892 us; speedup vs baseline: 1.3173x; 1.3173x over previous
//
#include <hip/hip_runtime.h>
#include <stdint.h>

typedef __attribute__((ext_vector_type(4))) int   i32x4;
typedef __attribute__((ext_vector_type(8))) short bf16x8;
typedef __attribute__((ext_vector_type(4))) float f32x4;

#define DEV static __device__ __forceinline__

constexpr int  kB = 128, kT = 512, kD = 512, kH = 512;
constexpr int  kGC = 2048;               // 4*H
constexpr int  ROWS = 32;                // batch rows per block
constexpr int  NG = 4;                   // batch groups
constexpr int  NJ = 32;                  // column-slice blocks per cluster
constexpr int  NTHREADS = 512;
constexpr size_t SLOT_ELEMS = (size_t)kB * kH;            // bf16 elems per ring slot -> 128 KB
constexpr size_t WIMG_ELEMS = (size_t)2 * NJ * 4 * 32 * 512; // 4,194,304 bf16
constexpr size_t WIMG_BYTES = WIMG_ELEMS * 2;             // 8 MB
constexpr int  RFULL = kT + 1;           // 513
constexpr int  FLAG_STRIDE = 128;        // one cacheline per (l,g,t); bytes 0..31 used (one per j)
constexpr size_t FLAG_TOTAL = (size_t)2 * NG * kT * FLAG_STRIDE; // 512 KB

DEV ushort f2bf(float f) {
  uint32_t u = __float_as_uint(f);
  u += 0x7fff + ((u >> 16) & 1);        // round-to-nearest-even
  return (ushort)(u >> 16);
}
DEV int pk2(float a, float b) { return (int)((uint32_t)f2bf(a) | ((uint32_t)f2bf(b) << 16)); }
DEV float sigf(float v)  { return 1.f / (1.f + __expf(-v)); }
DEV float tanhf_(float v){ return 1.f - 2.f / (__expf(2.f * v) + 1.f); }

DEV uint64_t ald64(const uint64_t* p) {
  return __hip_atomic_load(p, __ATOMIC_RELAXED, __HIP_MEMORY_SCOPE_AGENT);
}

// Wave-uniform broadcast poll: ALL lanes load the SAME 32-byte flag region.
DEV void poll32(const uint8_t* fb) {
  const uint64_t* p = reinterpret_cast<const uint64_t*>(fb);
  constexpr uint64_t ONE = 0x0101010101010101ull;
  for (;;) {
    uint64_t a = ald64(p) & ald64(p + 1) & ald64(p + 2) & ald64(p + 3);
    if (a == ONE) return;
    __builtin_amdgcn_s_sleep(1);
  }
}

// ---- prep: W (L,1024,2048) fp32 -> bf16 MFMA B-fragment image ----
__global__ void prep_w(const float* __restrict__ W, ushort* __restrict__ wimg) {
  uint32_t idx = blockIdx.x * 256u + threadIdx.x;
  int e = idx & 7, lane = (idx >> 3) & 63, ks = (idx >> 9) & 31;
  int G = (idx >> 14) & 3, j = (idx >> 16) & 31, l = (idx >> 21) & 1;
  int k = ks * 32 + ((lane >> 4) << 3) + e;
  int c = G * 512 + j * 16 + (lane & 15);
  wimg[idx] = f2bf(W[(size_t)l * 1024 * 2048 + (size_t)k * 2048 + c]);
}

// ---- prep: initial h (hiddens[l][0]) fp32 -> ring slot 0 bf16 ----
__global__ void prep_init(const float* __restrict__ hiddens, ushort* __restrict__ r0, ushort* __restrict__ r1) {
  uint32_t idx = blockIdx.x * 256u + threadIdx.x;   // 0 .. 2*65536-1
  int l = idx >> 16; uint32_t r = idx & 65535u;
  ushort v = f2bf(hiddens[(size_t)(l * 2 + 0) * 65536 + r]);
  (l ? r1 : r0)[r] = v;
}

// Bulk-stage 32 rows x 512 cols bf16 from a ring slot into a swizzled LDS half-tile.
DEV void stage_h(ushort* Ab, const ushort* rbase, int g, int tid) {
  #pragma unroll
  for (int p = 0; p < 4; ++p) {
    int o = (tid + p * NTHREADS) * 16, row = o >> 10, kb = o & 1023;
    i32x4 v = *reinterpret_cast<const i32x4*>(rbase + (size_t)(g * ROWS + row) * kH + (kb >> 1));
    *reinterpret_cast<i32x4*>(reinterpret_cast<char*>(Ab) + ((row * 1024 + kb) ^ ((row & 7) << 4))) = v;
  }
}

// gbuf index with bank-deconflicting column swizzle: lane-groups (rows r, r+4,
// r+8, r+12 written simultaneously) land on disjoint bank quads.
DEV int gsw(int r, int c) { return r * 16 + (c ^ ((((r) >> 2) & 3) << 2)); }

// ======================= BIG path: r3 order + Gp-dedupe + ks-split =======================
// Wave roles (8 waves): wv = kq*4 + Gp*2 + rf
//   kq = wv>>2      : k-slice within each K-half (8 of 16 ksteps)
//   Gp = (wv>>1)&1  : gate pair {2Gp, 2Gp+1} — ONE A-frag read feeds TWO mfma
//   rf = wv&1       : row fragment (16 rows)
// Temporal order is r3's, verbatim. Both MFMA phases use all 8 waves.
__launch_bounds__(NTHREADS, 1)
__global__ void lstm_v5(const float* __restrict__ x, const float* __restrict__ hiddens,
                        const float* __restrict__ bias, const ushort* __restrict__ wimg,
                        ushort* __restrict__ ring0, ushort* __restrict__ ring1,
                        uint8_t* __restrict__ flags, float* __restrict__ out) {
  __shared__ ushort AbufX[ROWS * 512];    // 32 KB: input half (k=0..511)
  __shared__ ushort AbufH[ROWS * 512];    // 32 KB: recurrent half (k=512..1023)
  __shared__ float  gbuf[2][4][ROWS * 16]; // raw gate partials [kq][gate][swizzled r*16+c]

  const int tid  = threadIdx.x;
  const int lane = tid & 63;
  const int wv   = tid >> 6;
  const int kq   = wv >> 2;               // k-slice
  const int Gp   = (wv >> 1) & 1;         // gate pair
  const int rf   = wv & 1;                // row-fragment
  const int j    = blockIdx.x & 31;       // column slice
  const int g    = (blockIdx.x >> 5) & 3; // batch group
  const int l    = blockIdx.x >> 7;       // layer

  __threadfence();  // entry agent fence: kill cross-replay stale cache lines

  // W fragments: 2 gates x (8 X-ksteps + 8 H-ksteps) of this wave's k-slice
  i32x4 wrA[16], wrB[16];
  {
    const int GA = 2 * Gp, GB = 2 * Gp + 1;
    const ushort* baseA = wimg + (((size_t)(l * NJ + j) * 4 + GA) * 32) * 512 + lane * 8;
    const ushort* baseB = wimg + (((size_t)(l * NJ + j) * 4 + GB) * 32) * 512 + lane * 8;
    #pragma unroll
    for (int s = 0; s < 8; ++s) {
      wrA[s]     = *reinterpret_cast<const i32x4*>(baseA + (kq * 8 + s) * 512);
      wrA[8 + s] = *reinterpret_cast<const i32x4*>(baseA + (16 + kq * 8 + s) * 512);
      wrB[s]     = *reinterpret_cast<const i32x4*>(baseB + (kq * 8 + s) * 512);
      wrB[8 + s] = *reinterpret_cast<const i32x4*>(baseB + (16 + kq * 8 + s) * 512);
    }
  }
  // per-update-thread bias (4 gates) and register-resident cell state
  const int urow = tid >> 4, ucol = tid & 15;
  const float b0 = bias[l * kGC + 0 * 512 + j * 16 + ucol];
  const float b1 = bias[l * kGC + 1 * 512 + j * 16 + ucol];
  const float b2 = bias[l * kGC + 2 * 512 + j * 16 + ucol];
  const float b3 = bias[l * kGC + 3 * 512 + j * 16 + ucol];
  float creg = hiddens[((size_t)(l * 2 + 1) * kB + (g * ROWS + urow)) * kH + j * 16 + ucol];

  ushort* rrec = l ? ring1 : ring0;
  uint8_t* myflags = flags + (size_t)(l * NG + g) * kT * FLAG_STRIDE;
  const uint8_t* xflags = flags + (size_t)g * kT * FLAG_STRIDE;  // layer-0 cluster

  const int arow  = rf * 16 + (lane & 15);
  const int koff  = (lane >> 4) << 3;
  const int abase = arow * 1024;
  const int aswz  = (arow & 7) << 4;
  const int uswz  = gsw(urow, ucol);

  // x-prefetch registers (layer 0): one step's 32x512 f32 tile, 128B/thread
  f32x4 xr[8];
  if (l == 0) {
    #pragma unroll
    for (int p = 0; p < 4; ++p) {
      int o = (tid + p * NTHREADS) * 16, row = o >> 10, kb = o & 1023;
      const float* src = x + ((size_t)(g * ROWS + row) * kT + 0) * kD + (kb >> 1);
      xr[2 * p]     = *reinterpret_cast<const f32x4*>(src);
      xr[2 * p + 1] = *reinterpret_cast<const f32x4*>(src + 4);
    }
  }

  for (int t = 0; t < kT; ++t) {
    // ---------- phase X: AbufX ready-up ----------
    if (l == 0) {
      #pragma unroll
      for (int p = 0; p < 4; ++p) {
        int o = (tid + p * NTHREADS) * 16, row = o >> 10, kb = o & 1023;
        i32x4 v;
        v[0] = pk2(xr[2 * p][0], xr[2 * p][1]);         v[1] = pk2(xr[2 * p][2], xr[2 * p][3]);
        v[2] = pk2(xr[2 * p + 1][0], xr[2 * p + 1][1]); v[3] = pk2(xr[2 * p + 1][2], xr[2 * p + 1][3]);
        *reinterpret_cast<i32x4*>(reinterpret_cast<char*>(AbufX) + ((row * 1024 + kb) ^ ((row & 7) << 4))) = v;
      }
    } else {
      poll32(xflags + (size_t)t * FLAG_STRIDE);        // layer0 finished step t
      stage_h(AbufX, ring0 + (size_t)(t + 1) * SLOT_ELEMS, g, tid);
    }
    __syncthreads();                                   // S1: AbufX ready

    // ---------- x-prefetch issue for t+1 (overlaps all MFMA below) ----------
    if (l == 0 && t + 1 < kT) {
      #pragma unroll
      for (int p = 0; p < 4; ++p) {
        int o = (tid + p * NTHREADS) * 16, row = o >> 10, kb = o & 1023;
        const float* src = x + ((size_t)(g * ROWS + row) * kT + (t + 1)) * kD + (kb >> 1);
        xr[2 * p]     = *reinterpret_cast<const f32x4*>(src);
        xr[2 * p + 1] = *reinterpret_cast<const f32x4*>(src + 4);
      }
    }

    // ---------- half 0 MFMA: all 8 waves, 1 frag read -> 2 mfma ----------
    f32x4 accA = {}, accB = {};
    #pragma unroll
    for (int s = 0; s < 8; ++s) {
      int ks = kq * 8 + s;
      int off = (abase + ((ks * 32 + koff) << 1)) ^ aswz;
      i32x4 av = *reinterpret_cast<const i32x4*>(reinterpret_cast<const char*>(AbufX) + off);
      accA = __builtin_amdgcn_mfma_f32_16x16x32_bf16(
               *reinterpret_cast<bf16x8*>(&av), *reinterpret_cast<bf16x8*>(&wrA[s]), accA, 0, 0, 0);
      accB = __builtin_amdgcn_mfma_f32_16x16x32_bf16(
               *reinterpret_cast<bf16x8*>(&av), *reinterpret_cast<bf16x8*>(&wrB[s]), accB, 0, 0, 0);
    }

    // ---------- poll peers' h_{t-1}, then stage recurrent half ----------
    if (t > 0) poll32(myflags + (size_t)(t - 1) * FLAG_STRIDE);
    stage_h(AbufH, rrec + (size_t)t * SLOT_ELEMS, g, tid);
    __syncthreads();                                   // S2: AbufH ready

    // ---------- half 1 MFMA ----------
    #pragma unroll
    for (int s = 0; s < 8; ++s) {
      int ks = kq * 8 + s;
      int off = (abase + ((ks * 32 + koff) << 1)) ^ aswz;
      i32x4 av = *reinterpret_cast<const i32x4*>(reinterpret_cast<const char*>(AbufH) + off);
      accA = __builtin_amdgcn_mfma_f32_16x16x32_bf16(
               *reinterpret_cast<bf16x8*>(&av), *reinterpret_cast<bf16x8*>(&wrA[8 + s]), accA, 0, 0, 0);
      accB = __builtin_amdgcn_mfma_f32_16x16x32_bf16(
               *reinterpret_cast<bf16x8*>(&av), *reinterpret_cast<bf16x8*>(&wrB[8 + s]), accB, 0, 0, 0);
    }

    // ---------- raw partial exchange (swizzled, conflict-free) ----------
    #pragma unroll
    for (int q = 0; q < 4; ++q) {
      int r = rf * 16 + ((lane >> 4) << 2) + q, c = lane & 15;
      int idx = gsw(r, c);
      gbuf[kq][2 * Gp][idx]     = accA[q];
      gbuf[kq][2 * Gp + 1][idx] = accB[q];
    }
    __syncthreads();                                   // S3: partials ready

    // ---------- fused sum + activation + c/h update + publish ----------
    float hh;
    {
      float iv = sigf  (gbuf[0][0][uswz] + gbuf[1][0][uswz] + b0);
      float fv = sigf  (gbuf[0][1][uswz] + gbuf[1][1][uswz] + b1);
      float gv = tanhf_(gbuf[0][2][uswz] + gbuf[1][2][uswz] + b2);
      float ov = sigf  (gbuf[0][3][uswz] + gbuf[1][3][uswz] + b3);
      creg = fv * creg + iv * gv;
      hh = ov * tanhf_(creg);
      uint32_t me    = f2bf(hh);
      uint32_t other = (uint32_t)__shfl_xor((int)me, 1);  // partner col^1, same wave
      if (!(ucol & 1)) {
        uint32_t pkv = me | (other << 16);
        uint32_t* dst = (uint32_t*)(rrec + (size_t)(t + 1) * SLOT_ELEMS
                                    + (size_t)(g * ROWS + urow) * kH + j * 16 + ucol);
        __hip_atomic_store(dst, pkv, __ATOMIC_RELAXED, __HIP_MEMORY_SCOPE_AGENT);
      }
    }
    asm volatile("s_waitcnt vmcnt(0)" ::: "memory");   // drain publish (xr prefetch long done)
    __syncthreads();                                   // S_p: all waves drained
    if (tid == 0)
      __hip_atomic_store(myflags + (size_t)t * FLAG_STRIDE + j, (uint8_t)1,
                         __ATOMIC_RELAXED, __HIP_MEMORY_SCOPE_AGENT);

    // bulk output writes AFTER the flag
    {
      int b = g * ROWS + urow;
      if (l == 1) out[((size_t)b * kT + t) * kH + j * 16 + ucol] = hh;
      if (t == kT - 1) {
        size_t hb = (size_t)kB * kT * kH;
        out[hb + ((size_t)(l * 2 + 0) * kB + b) * kH + j * 16 + ucol] = hh;
        out[hb + ((size_t)(l * 2 + 1) * kB + b) * kH + j * 16 + ucol] = creg;
      }
    }
  }
}

// ======================= small-workspace fallback (round-0 proven path) =======================

template<bool BIG>
DEV void stage_ring(ushort* Abuf_, const ushort* rbase, int g, int tid) {
  #pragma unroll
  for (int p = 0; p < 4; ++p) {
    int o = (tid + p * NTHREADS) * 16;
    int row = o >> 10, kb = o & 1023;
    const ushort* src = rbase + (size_t)(g * ROWS + row) * kH + (kb >> 1);
    i32x4 v;
    if (BIG) {
      v = *reinterpret_cast<const i32x4*>(src);
    } else {
      uint64_t lo = __hip_atomic_load((const uint64_t*)src,       __ATOMIC_RELAXED, __HIP_MEMORY_SCOPE_AGENT);
      uint64_t hi = __hip_atomic_load((const uint64_t*)(src + 4), __ATOMIC_RELAXED, __HIP_MEMORY_SCOPE_AGENT);
      v[0] = (int)(uint32_t)lo; v[1] = (int)(uint32_t)(lo >> 32);
      v[2] = (int)(uint32_t)hi; v[3] = (int)(uint32_t)(hi >> 32);
    }
    *reinterpret_cast<i32x4*>(reinterpret_cast<char*>(Abuf_) + ((row * 1024 + kb) ^ ((row & 7) << 4))) = v;
  }
}

template<bool BIG>
__launch_bounds__(NTHREADS, 2)
__global__ void lstm_main(const float* __restrict__ x, const float* __restrict__ hiddens,
                          const float* __restrict__ bias, const ushort* __restrict__ wimg,
                          ushort* __restrict__ ring0, ushort* __restrict__ ring1,
                          int* __restrict__ cnt, int* __restrict__ cons0,
                          float* __restrict__ out, int R0, int R1) {
  __shared__ ushort Abuf[ROWS * 512];
  __shared__ float  gbuf[4][ROWS][16];
  __shared__ float  cbuf[ROWS][16];
  __shared__ float  hbuf[ROWS][16];

  const int tid  = threadIdx.x;
  const int lane = tid & 63;
  const int wv   = tid >> 6;
  const int G    = wv & 3;
  const int rf   = wv >> 2;
  const int j    = blockIdx.x & 31;
  const int g    = (blockIdx.x >> 5) & 3;
  const int l    = blockIdx.x >> 7;

  __threadfence();

  i32x4 wr[32];
  {
    const ushort* base = wimg + (((size_t)(l * NJ + j) * 4 + G) * 32) * 512 + lane * 8;
    #pragma unroll
    for (int ks = 0; ks < 32; ++ks)
      wr[ks] = *reinterpret_cast<const i32x4*>(base + ks * 512);
  }
  const float bval = bias[l * kGC + G * 512 + j * 16 + (lane & 15)];
  {
    int row = tid >> 4, col = tid & 15;
    cbuf[row][col] = hiddens[((size_t)(l * 2 + 1) * kB + (g * ROWS + row)) * kH + j * 16 + col];
  }
  int* mycnt = cnt + (l * NG + g) * kT;
  int* c0cnt = cnt + g * kT;
  ushort* rrec = l ? ring1 : ring0;
  const int Rrec = l ? R1 : R0;

  const int arow  = rf * 16 + (lane & 15);
  const int koff  = (lane >> 4) << 3;
  const int abase = arow * 1024;
  const int aswz  = (arow & 7) << 4;

  __syncthreads();

  for (int t = 0; t < kT; ++t) {
    if (l == 1) {
      if (tid == 0) {
        while (__hip_atomic_load(&c0cnt[t], __ATOMIC_RELAXED, __HIP_MEMORY_SCOPE_AGENT) < NJ)
          __builtin_amdgcn_s_sleep(2);
      }
      __syncthreads();
      stage_ring<BIG>(Abuf, ring0 + (size_t)((t + 1) % R0) * SLOT_ELEMS, g, tid);
    } else {
      #pragma unroll
      for (int p = 0; p < 4; ++p) {
        int o = (tid + p * NTHREADS) * 16;
        int row = o >> 10, kb = o & 1023;
        const float* src = x + ((size_t)(g * ROWS + row) * kT + t) * kD + (kb >> 1);
        f32x4 f0 = *reinterpret_cast<const f32x4*>(src);
        f32x4 f1 = *reinterpret_cast<const f32x4*>(src + 4);
        i32x4 v;
        v[0] = pk2(f0[0], f0[1]); v[1] = pk2(f0[2], f0[3]);
        v[2] = pk2(f1[0], f1[1]); v[3] = pk2(f1[2], f1[3]);
        *reinterpret_cast<i32x4*>(reinterpret_cast<char*>(Abuf) + ((row * 1024 + kb) ^ ((row & 7) << 4))) = v;
      }
    }
    __syncthreads();
    if (!BIG && l == 1 && tid == 0)
      __hip_atomic_fetch_add(&cons0[g * kT + t], 1, __ATOMIC_RELAXED, __HIP_MEMORY_SCOPE_AGENT);

    f32x4 acc = {};
    #pragma unroll
    for (int ks = 0; ks < 16; ++ks) {
      int off = (abase + ((ks * 32 + koff) << 1)) ^ aswz;
      i32x4 av = *reinterpret_cast<const i32x4*>(reinterpret_cast<const char*>(Abuf) + off);
      acc = __builtin_amdgcn_mfma_f32_16x16x32_bf16(
              *reinterpret_cast<bf16x8*>(&av), *reinterpret_cast<bf16x8*>(&wr[ks]), acc, 0, 0, 0);
    }
    __syncthreads();

    if (t > 0) {
      if (tid == 0) {
        while (__hip_atomic_load(&mycnt[t - 1], __ATOMIC_RELAXED, __HIP_MEMORY_SCOPE_AGENT) < NJ)
          __builtin_amdgcn_s_sleep(2);
        if (!BIG && l == 0 && t >= R0) {
          while (__hip_atomic_load(&cons0[g * kT + (t - R0)], __ATOMIC_RELAXED, __HIP_MEMORY_SCOPE_AGENT) < NJ)
            __builtin_amdgcn_s_sleep(2);
        }
      }
      __syncthreads();
    }
    stage_ring<BIG>(Abuf, rrec + (size_t)(t % Rrec) * SLOT_ELEMS, g, tid);
    __syncthreads();

    #pragma unroll
    for (int ks = 0; ks < 16; ++ks) {
      int off = (abase + ((ks * 32 + koff) << 1)) ^ aswz;
      i32x4 av = *reinterpret_cast<const i32x4*>(reinterpret_cast<const char*>(Abuf) + off);
      acc = __builtin_amdgcn_mfma_f32_16x16x32_bf16(
              *reinterpret_cast<bf16x8*>(&av), *reinterpret_cast<bf16x8*>(&wr[16 + ks]), acc, 0, 0, 0);
    }

    #pragma unroll
    for (int q = 0; q < 4; ++q) {
      float v2 = acc[q] + bval;
      v2 = (G == 2) ? tanhf_(v2) : sigf(v2);
      gbuf[G][rf * 16 + ((lane >> 4) << 2) + q][lane & 15] = v2;
    }
    __syncthreads();

    {
      int row = tid >> 4, col = tid & 15;
      float iv = gbuf[0][row][col], fv = gbuf[1][row][col];
      float gv = gbuf[2][row][col], ov = gbuf[3][row][col];
      float cc = fv * cbuf[row][col] + iv * gv;
      cbuf[row][col] = cc;
      float hh = ov * tanhf_(cc);
      hbuf[row][col] = hh;
      int b = g * ROWS + row;
      if (l == 1) out[((size_t)b * kT + t) * kH + j * 16 + col] = hh;
      if (t == kT - 1) {
        size_t hb = (size_t)kB * kT * kH;
        out[hb + ((size_t)(l * 2 + 0) * kB + b) * kH + j * 16 + col] = hh;
        out[hb + ((size_t)(l * 2 + 1) * kB + b) * kH + j * 16 + col] = cc;
      }
    }
    __syncthreads();

    if (tid < 256) {
      int row = tid >> 3, cp = tid & 7;
      uint32_t pkv = (uint32_t)f2bf(hbuf[row][2 * cp]) | ((uint32_t)f2bf(hbuf[row][2 * cp + 1]) << 16);
      uint32_t* dst = (uint32_t*)(rrec + (size_t)((t + 1) % Rrec) * SLOT_ELEMS
                                  + (size_t)(g * ROWS + row) * kH + j * 16 + 2 * cp);
      __hip_atomic_store(dst, pkv, __ATOMIC_RELAXED, __HIP_MEMORY_SCOPE_AGENT);
    }
    asm volatile("s_waitcnt vmcnt(0)" ::: "memory");
    __syncthreads();
    if (tid == 0)
      __hip_atomic_fetch_add(&mycnt[t], 1, __ATOMIC_RELAXED, __HIP_MEMORY_SCOPE_AGENT);
  }
}

extern "C" void kernel_launch(void* const* d_in, const int* in_sizes, int n_in,
                              void* d_out, int out_size, void* d_ws, size_t ws_size,
                              hipStream_t stream) {
  const float* x  = (const float*)d_in[0];
  const float* hd = (const float*)d_in[1];
  const float* W  = (const float*)d_in[2];
  const float* b  = (const float*)d_in[3];
  float* out = (float*)d_out;

  char* ws = (char*)d_ws;
  ushort* wimg = (ushort*)ws;
  uint8_t* flags = (uint8_t*)(ws + WIMG_BYTES);                // 512 KB
  int* cnt  = (int*)(ws + WIMG_BYTES + FLAG_TOTAL);            // 16 KB (fallback)
  int* cons = (int*)(ws + WIMG_BYTES + FLAG_TOTAL + 16384);    // 8 KB  (fallback)
  size_t ringoff = WIMG_BYTES + FLAG_TOTAL + 32768;
  size_t avail = ws_size > ringoff ? ws_size - ringoff : 0;
  long rmax = (long)(avail / (2 * SLOT_ELEMS * 2));
  int R = (rmax >= RFULL) ? RFULL : (rmax >= 16 ? 16 : (rmax >= 2 ? (int)rmax : 2));
  ushort* ring0 = (ushort*)(ws + ringoff);
  ushort* ring1 = ring0 + (size_t)R * SLOT_ELEMS;

  prep_w<<<(int)(WIMG_ELEMS / 256), 256, 0, stream>>>(W, wimg);
  prep_init<<<(2 * kB * kH) / 256, 256, 0, stream>>>(hd, ring0, ring1);
  if (R == RFULL) {
    hipMemsetAsync(flags, 0, FLAG_TOTAL, stream);
    lstm_v5<<<256, NTHREADS, 0, stream>>>(x, hd, b, wimg, ring0, ring1, flags, out);
  } else {
    hipMemsetAsync(ws + WIMG_BYTES + FLAG_TOTAL, 0, 32768, stream);
    lstm_main<false><<<256, NTHREADS, 0, stream>>>(x, hd, b, wimg, ring0, ring1, cnt, cons, out, R, R);
  }
}